// Round 11
// baseline (269.555 us; speedup 1.0000x reference)
//
#include <hip/hip_runtime.h>
#include <hip/hip_bf16.h>

// channel_cluster_layer: pool -> fc1(sigmoid) -> fc2(sigmoid) -> weighted channel reduce
// B=32, C=2048, L=891 (9*11*9), P=8, HID=8192, NOUT=16384
// R10=242.7us. R11: fc1 split-K 8 (kc=256 -> real pipeline, was degenerate at kc=128);
// ein c-split 16 + unroll 16 (32 waves/CU). fc2 unchanged (at byte floor per R9).
#define BB 32
#define CC 2048
#define LL 891
#define PP 8
#define HIDN 8192
#define NOUT 16384

typedef __attribute__((ext_vector_type(4))) float f32x4;
typedef __attribute__((ext_vector_type(8))) __bf16 bf16x8;

// ---------- kernel 1: global average pool, one wave per (b,c) row, float4 body ----------
__global__ __launch_bounds__(256) void pool_kernel(const float* __restrict__ x,
                                                   __hip_bfloat16* __restrict__ pooled) {
  int wid = threadIdx.x >> 6, lane = threadIdx.x & 63;
  int row = blockIdx.x * 4 + wid;  // < 65536
  const float* r = x + (long)row * LL;
  int align = (4 - ((row * 3) & 3)) & 3;       // scalar head elements (891%4==3)
  int nvec = (LL - align) >> 2;                // float4 count
  int rem = LL - align - (nvec << 2);          // scalar tail
  const f32x4* v = (const f32x4*)(r + align);
  float s = 0.f;
  for (int i = lane; i < nvec; i += 64) {
    f32x4 q = v[i];
    s += (q.x + q.y) + (q.z + q.w);
  }
  if (lane < align) s += r[lane];
  if (lane < rem) s += r[align + (nvec << 2) + lane];
#pragma unroll
  for (int off = 32; off > 0; off >>= 1) s += __shfl_xor(s, off);
  if (lane == 0) pooled[row] = __float2bfloat16(s * (1.0f / (float)LL));
}

// f32x8 -> bf16x8 via native casts (compiler emits v_cvt_pk_bf16_f32, RNE)
__device__ __forceinline__ bf16x8 cvt8(f32x4 a, f32x4 b) {
  bf16x8 r;
  r[0] = (__bf16)a.x; r[1] = (__bf16)a.y; r[2] = (__bf16)a.z; r[3] = (__bf16)a.w;
  r[4] = (__bf16)b.x; r[5] = (__bf16)b.y; r[6] = (__bf16)b.z; r[7] = (__bf16)b.w;
  return r;
}

// ---------- kernels 2/4: partial[32][N] = A[32][K](bf16) @ W[N][K](f32->bf16)^T ----------
// T n-tiles per wave (n0 + t*64), 64-k double-step, depth-2 register pipeline.
// Per iter: 4T W-loads (16B) + 4 A-loads, 4T MFMA. All arrays statically indexed.
// grid: (N/(64T), nsplit); block 256 = 4 waves.
template <int T>
__global__ __launch_bounds__(256) void fc_kernel(const __hip_bfloat16* __restrict__ A,
                                                 const float* __restrict__ W,
                                                 float* __restrict__ partial,
                                                 int N, int K, int kc) {
  int lane = threadIdx.x & 63, wv = threadIdx.x >> 6;
  int n0 = blockIdx.x * (64 * T) + wv * 16;
  int k0 = blockIdx.y * kc;
  int r = lane & 15, kg = lane >> 4;

  const float* Wp[T];
#pragma unroll
  for (int t = 0; t < T; ++t) Wp[t] = W + (long)(n0 + t * 64 + r) * K + k0 + kg * 8;
  const __hip_bfloat16* Ap0 = A + (long)r * K + k0 + kg * 8;
  const __hip_bfloat16* Ap1 = Ap0 + 16 * (long)K;
  long base = (long)blockIdx.y * 32 * N + n0 + r;

  f32x4 acc[T][2];
#pragma unroll
  for (int t = 0; t < T; ++t) {
    acc[t][0] = (f32x4){0.f, 0.f, 0.f, 0.f};
    acc[t][1] = (f32x4){0.f, 0.f, 0.f, 0.f};
  }

  f32x4 cw[T][4];
  int4 ca[4];
#pragma unroll
  for (int t = 0; t < T; ++t) {
    cw[t][0] = *(const f32x4*)(Wp[t]);
    cw[t][1] = *(const f32x4*)(Wp[t] + 4);
    cw[t][2] = *(const f32x4*)(Wp[t] + 32);
    cw[t][3] = *(const f32x4*)(Wp[t] + 36);
  }
  ca[0] = *(const int4*)(Ap0); ca[1] = *(const int4*)(Ap0 + 32);
  ca[2] = *(const int4*)(Ap1); ca[3] = *(const int4*)(Ap1 + 32);

#define FC_COMPUTE()                                                                 \
  {                                                                                  \
    bf16x8 va00 = __builtin_bit_cast(bf16x8, ca[0]);                                 \
    bf16x8 va01 = __builtin_bit_cast(bf16x8, ca[1]);                                 \
    bf16x8 va10 = __builtin_bit_cast(bf16x8, ca[2]);                                 \
    bf16x8 va11 = __builtin_bit_cast(bf16x8, ca[3]);                                 \
    _Pragma("unroll")                                                                \
    for (int t = 0; t < T; ++t) {                                                    \
      bf16x8 b0 = cvt8(cw[t][0], cw[t][1]);                                          \
      bf16x8 b1 = cvt8(cw[t][2], cw[t][3]);                                          \
      acc[t][0] = __builtin_amdgcn_mfma_f32_16x16x32_bf16(va00, b0, acc[t][0], 0, 0, 0); \
      acc[t][1] = __builtin_amdgcn_mfma_f32_16x16x32_bf16(va10, b0, acc[t][1], 0, 0, 0); \
      acc[t][0] = __builtin_amdgcn_mfma_f32_16x16x32_bf16(va01, b1, acc[t][0], 0, 0, 0); \
      acc[t][1] = __builtin_amdgcn_mfma_f32_16x16x32_bf16(va11, b1, acc[t][1], 0, 0, 0); \
    }                                                                                \
  }

  for (int ks = 64; ks < kc; ks += 64) {
    f32x4 nw[T][4];
    int4 na[4];
#pragma unroll
    for (int t = 0; t < T; ++t) {
      nw[t][0] = *(const f32x4*)(Wp[t] + ks);
      nw[t][1] = *(const f32x4*)(Wp[t] + ks + 4);
      nw[t][2] = *(const f32x4*)(Wp[t] + ks + 32);
      nw[t][3] = *(const f32x4*)(Wp[t] + ks + 36);
    }
    na[0] = *(const int4*)(Ap0 + ks); na[1] = *(const int4*)(Ap0 + ks + 32);
    na[2] = *(const int4*)(Ap1 + ks); na[3] = *(const int4*)(Ap1 + ks + 32);
    FC_COMPUTE();
#pragma unroll
    for (int t = 0; t < T; ++t) {
      cw[t][0] = nw[t][0]; cw[t][1] = nw[t][1];
      cw[t][2] = nw[t][2]; cw[t][3] = nw[t][3];
    }
    ca[0] = na[0]; ca[1] = na[1]; ca[2] = na[2]; ca[3] = na[3];
  }
  FC_COMPUTE();
#undef FC_COMPUTE

  // C/D layout (m89-verified): col = lane&15 (-> n), row = (lane>>4)*4 + reg (-> b)
#pragma unroll
  for (int t = 0; t < T; ++t) {
#pragma unroll
    for (int j = 0; j < 4; ++j) {
      int row = kg * 4 + j;
      partial[base + t * 64 + (long)row * N] = acc[t][0][j];
      partial[base + t * 64 + (long)(row + 16) * N] = acc[t][1][j];
    }
  }
}

// ---------- kernels 3/5: reduce splits + bias + sigmoid, float4-wide ----------
__global__ __launch_bounds__(256) void fc_reduce_kernel(const float* __restrict__ part,
                                                        int nsplit, int MN, int N,
                                                        const float* __restrict__ bias,
                                                        float* __restrict__ outF,
                                                        __hip_bfloat16* __restrict__ outB) {
  int i4 = blockIdx.x * 256 + threadIdx.x;  // MN/4 lanes
  if (i4 * 4 >= MN) return;
  f32x4 s = {0.f, 0.f, 0.f, 0.f};
  for (int i = 0; i < nsplit; ++i) {
    f32x4 v = *(const f32x4*)(part + (long)i * MN + i4 * 4);
    s += v;
  }
  f32x4 bv = *(const f32x4*)(bias + ((i4 * 4) & (N - 1)));
  f32x4 g;
  g.x = 1.f / (1.f + __expf(-(s.x + bv.x)));
  g.y = 1.f / (1.f + __expf(-(s.y + bv.y)));
  g.z = 1.f / (1.f + __expf(-(s.z + bv.z)));
  g.w = 1.f / (1.f + __expf(-(s.w + bv.w)));
  if (outF) *(f32x4*)(outF + i4 * 4) = g;
  if (outB) {
    union { __hip_bfloat16 h[4]; unsigned long long u; } pk;
    pk.h[0] = __float2bfloat16(g.x); pk.h[1] = __float2bfloat16(g.y);
    pk.h[2] = __float2bfloat16(g.z); pk.h[3] = __float2bfloat16(g.w);
    *((unsigned long long*)outB + i4) = pk.u;
  }
}

// ---------- kernel 6: weighted[b][p][l] partials = sum_c g[b][p*C+c] * x[b][c][l] ----------
// grid (4 l-blocks, 32 b, 16 c-splits of 128); g block-uniform -> scalar loads.
__global__ __launch_bounds__(256) void ein_partial_kernel(const float* __restrict__ x,
                                                          const float* __restrict__ g,
                                                          float* __restrict__ part) {
  int l = blockIdx.x * 256 + threadIdx.x;
  int b = blockIdx.y;
  int s = blockIdx.z;
  int c0 = s * 128;
  const float* xp = x + ((long)b * CC + c0) * LL + l;
  const float* gp = g + (long)b * NOUT + c0;
  bool act = l < LL;
  float acc[PP] = {0.f, 0.f, 0.f, 0.f, 0.f, 0.f, 0.f, 0.f};
#pragma unroll 16
  for (int i = 0; i < 128; ++i) {
    float xv = act ? xp[(long)i * LL] : 0.f;
#pragma unroll
    for (int p = 0; p < PP; ++p) acc[p] += gp[p * CC + i] * xv;
  }
  if (act) {
    float* pp = part + (long)(s * BB + b) * PP * LL + l;
#pragma unroll
    for (int p = 0; p < PP; ++p) pp[(long)p * LL] = acc[p];
  }
}

// ---------- kernel 7: reduce c-splits, /C, float4-wide ----------
__global__ __launch_bounds__(256) void ein_reduce_kernel(const float* __restrict__ part,
                                                         float* __restrict__ outw) {
  int i4 = blockIdx.x * 256 + threadIdx.x;  // 57024 = 891*256/4 lanes
  if (i4 >= (BB * PP * LL) / 4) return;
  f32x4 s = {0.f, 0.f, 0.f, 0.f};
#pragma unroll
  for (int i = 0; i < 16; ++i) {
    f32x4 v = *(const f32x4*)(part + (long)i * (BB * PP * LL) + i4 * 4);
    s += v;
  }
  const float inv = 1.0f / (float)CC;
  f32x4 o = s * inv;
  *(f32x4*)(outw + i4 * 4) = o;
}

extern "C" void kernel_launch(void* const* d_in, const int* in_sizes, int n_in,
                              void* d_out, int out_size, void* d_ws, size_t ws_size,
                              hipStream_t stream) {
  const float* x     = (const float*)d_in[0];
  const float* fc1_w = (const float*)d_in[1];
  const float* fc1_b = (const float*)d_in[2];
  const float* fc2_w = (const float*)d_in[3];
  const float* fc2_b = (const float*)d_in[4];
  float* out = (float*)d_out;

  char* ws = (char*)d_ws;
  __hip_bfloat16* pooled = (__hip_bfloat16*)ws;              // 32*2048*2   = 128 KB
  __hip_bfloat16* hbuf   = (__hip_bfloat16*)(ws + 131072);   // 32*8192*2   = 512 KB
  float* part            = (float*)(ws + 655360);            // max 33.6 MB (reused per stage)

  pool_kernel<<<BB * CC / 4, 256, 0, stream>>>(x, pooled);

  // fc1: T=2, N=8192, K=2048, 8-way split-K (kc=256 -> 4 pipeline iters) -> 512 blocks
  fc_kernel<2><<<dim3(HIDN / 128, 8), 256, 0, stream>>>(pooled, fc1_w, part, HIDN, CC, CC / 8);
  fc_reduce_kernel<<<BB * HIDN / 1024, 256, 0, stream>>>(part, 8, BB * HIDN, HIDN, fc1_b,
                                                         nullptr, hbuf);

  // fc2: T=4, N=16384, K=8192, 16-way split-K (kc=512) -> 1024 blocks
  fc_kernel<4><<<dim3(NOUT / 256, 16), 256, 0, stream>>>(hbuf, fc2_w, part, NOUT, HIDN, HIDN / 16);
  fc_reduce_kernel<<<BB * NOUT / 1024, 256, 0, stream>>>(part, 16, BB * NOUT, NOUT, fc2_b,
                                                         out, nullptr);

  // ein: 16 c-splits of 128 -> 2048 blocks (32 waves/CU)
  ein_partial_kernel<<<dim3(4, BB, 16), 256, 0, stream>>>(x, out, part);
  ein_reduce_kernel<<<(BB * PP * LL / 4 + 255) / 256, 256, 0, stream>>>(part, out + BB * PP * CC);
}

// Round 12
// 241.896 us; speedup vs baseline: 1.1143x; 1.1143x over previous
//
#include <hip/hip_runtime.h>
#include <hip/hip_bf16.h>

// channel_cluster_layer: pool -> fc1(sigmoid) -> fc2(sigmoid) -> weighted channel reduce
// B=32, C=2048, L=891 (9*11*9), P=8, HID=8192, NOUT=16384
// R11 (+27us) reverted: fc1 back to split-K 16, ein back to 8 c-splits (R10-measured).
// R12 single probe: fc2 T=4 -> T=2 (2048 blocks, 8/CU) to lift cold-miss concurrency.
#define BB 32
#define CC 2048
#define LL 891
#define PP 8
#define HIDN 8192
#define NOUT 16384

typedef __attribute__((ext_vector_type(4))) float f32x4;
typedef __attribute__((ext_vector_type(8))) __bf16 bf16x8;

// ---------- kernel 1: global average pool, one wave per (b,c) row, float4 body ----------
__global__ __launch_bounds__(256) void pool_kernel(const float* __restrict__ x,
                                                   __hip_bfloat16* __restrict__ pooled) {
  int wid = threadIdx.x >> 6, lane = threadIdx.x & 63;
  int row = blockIdx.x * 4 + wid;  // < 65536
  const float* r = x + (long)row * LL;
  int align = (4 - ((row * 3) & 3)) & 3;       // scalar head elements (891%4==3)
  int nvec = (LL - align) >> 2;                // float4 count
  int rem = LL - align - (nvec << 2);          // scalar tail
  const f32x4* v = (const f32x4*)(r + align);
  float s = 0.f;
  for (int i = lane; i < nvec; i += 64) {
    f32x4 q = v[i];
    s += (q.x + q.y) + (q.z + q.w);
  }
  if (lane < align) s += r[lane];
  if (lane < rem) s += r[align + (nvec << 2) + lane];
#pragma unroll
  for (int off = 32; off > 0; off >>= 1) s += __shfl_xor(s, off);
  if (lane == 0) pooled[row] = __float2bfloat16(s * (1.0f / (float)LL));
}

// f32x8 -> bf16x8 via native casts (compiler emits v_cvt_pk_bf16_f32, RNE)
__device__ __forceinline__ bf16x8 cvt8(f32x4 a, f32x4 b) {
  bf16x8 r;
  r[0] = (__bf16)a.x; r[1] = (__bf16)a.y; r[2] = (__bf16)a.z; r[3] = (__bf16)a.w;
  r[4] = (__bf16)b.x; r[5] = (__bf16)b.y; r[6] = (__bf16)b.z; r[7] = (__bf16)b.w;
  return r;
}

// ---------- kernels 2/4: partial[32][N] = A[32][K](bf16) @ W[N][K](f32->bf16)^T ----------
// T n-tiles per wave (n0 + t*64), 64-k double-step, depth-2 register pipeline.
// Per iter: 4T W-loads (16B) + 4 A-loads, 4T MFMA. All arrays statically indexed.
// grid: (N/(64T), nsplit); block 256 = 4 waves.
template <int T>
__global__ __launch_bounds__(256) void fc_kernel(const __hip_bfloat16* __restrict__ A,
                                                 const float* __restrict__ W,
                                                 float* __restrict__ partial,
                                                 int N, int K, int kc) {
  int lane = threadIdx.x & 63, wv = threadIdx.x >> 6;
  int n0 = blockIdx.x * (64 * T) + wv * 16;
  int k0 = blockIdx.y * kc;
  int r = lane & 15, kg = lane >> 4;

  const float* Wp[T];
#pragma unroll
  for (int t = 0; t < T; ++t) Wp[t] = W + (long)(n0 + t * 64 + r) * K + k0 + kg * 8;
  const __hip_bfloat16* Ap0 = A + (long)r * K + k0 + kg * 8;
  const __hip_bfloat16* Ap1 = Ap0 + 16 * (long)K;
  long base = (long)blockIdx.y * 32 * N + n0 + r;

  f32x4 acc[T][2];
#pragma unroll
  for (int t = 0; t < T; ++t) {
    acc[t][0] = (f32x4){0.f, 0.f, 0.f, 0.f};
    acc[t][1] = (f32x4){0.f, 0.f, 0.f, 0.f};
  }

  f32x4 cw[T][4];
  int4 ca[4];
#pragma unroll
  for (int t = 0; t < T; ++t) {
    cw[t][0] = *(const f32x4*)(Wp[t]);
    cw[t][1] = *(const f32x4*)(Wp[t] + 4);
    cw[t][2] = *(const f32x4*)(Wp[t] + 32);
    cw[t][3] = *(const f32x4*)(Wp[t] + 36);
  }
  ca[0] = *(const int4*)(Ap0); ca[1] = *(const int4*)(Ap0 + 32);
  ca[2] = *(const int4*)(Ap1); ca[3] = *(const int4*)(Ap1 + 32);

#define FC_COMPUTE()                                                                 \
  {                                                                                  \
    bf16x8 va00 = __builtin_bit_cast(bf16x8, ca[0]);                                 \
    bf16x8 va01 = __builtin_bit_cast(bf16x8, ca[1]);                                 \
    bf16x8 va10 = __builtin_bit_cast(bf16x8, ca[2]);                                 \
    bf16x8 va11 = __builtin_bit_cast(bf16x8, ca[3]);                                 \
    _Pragma("unroll")                                                                \
    for (int t = 0; t < T; ++t) {                                                    \
      bf16x8 b0 = cvt8(cw[t][0], cw[t][1]);                                          \
      bf16x8 b1 = cvt8(cw[t][2], cw[t][3]);                                          \
      acc[t][0] = __builtin_amdgcn_mfma_f32_16x16x32_bf16(va00, b0, acc[t][0], 0, 0, 0); \
      acc[t][1] = __builtin_amdgcn_mfma_f32_16x16x32_bf16(va10, b0, acc[t][1], 0, 0, 0); \
      acc[t][0] = __builtin_amdgcn_mfma_f32_16x16x32_bf16(va01, b1, acc[t][0], 0, 0, 0); \
      acc[t][1] = __builtin_amdgcn_mfma_f32_16x16x32_bf16(va11, b1, acc[t][1], 0, 0, 0); \
    }                                                                                \
  }

  for (int ks = 64; ks < kc; ks += 64) {
    f32x4 nw[T][4];
    int4 na[4];
#pragma unroll
    for (int t = 0; t < T; ++t) {
      nw[t][0] = *(const f32x4*)(Wp[t] + ks);
      nw[t][1] = *(const f32x4*)(Wp[t] + ks + 4);
      nw[t][2] = *(const f32x4*)(Wp[t] + ks + 32);
      nw[t][3] = *(const f32x4*)(Wp[t] + ks + 36);
    }
    na[0] = *(const int4*)(Ap0 + ks); na[1] = *(const int4*)(Ap0 + ks + 32);
    na[2] = *(const int4*)(Ap1 + ks); na[3] = *(const int4*)(Ap1 + ks + 32);
    FC_COMPUTE();
#pragma unroll
    for (int t = 0; t < T; ++t) {
      cw[t][0] = nw[t][0]; cw[t][1] = nw[t][1];
      cw[t][2] = nw[t][2]; cw[t][3] = nw[t][3];
    }
    ca[0] = na[0]; ca[1] = na[1]; ca[2] = na[2]; ca[3] = na[3];
  }
  FC_COMPUTE();
#undef FC_COMPUTE

  // C/D layout (m89-verified): col = lane&15 (-> n), row = (lane>>4)*4 + reg (-> b)
#pragma unroll
  for (int t = 0; t < T; ++t) {
#pragma unroll
    for (int j = 0; j < 4; ++j) {
      int row = kg * 4 + j;
      partial[base + t * 64 + (long)row * N] = acc[t][0][j];
      partial[base + t * 64 + (long)(row + 16) * N] = acc[t][1][j];
    }
  }
}

// ---------- kernels 3/5: reduce splits + bias + sigmoid, float4-wide ----------
__global__ __launch_bounds__(256) void fc_reduce_kernel(const float* __restrict__ part,
                                                        int nsplit, int MN, int N,
                                                        const float* __restrict__ bias,
                                                        float* __restrict__ outF,
                                                        __hip_bfloat16* __restrict__ outB) {
  int i4 = blockIdx.x * 256 + threadIdx.x;  // MN/4 lanes
  if (i4 * 4 >= MN) return;
  f32x4 s = {0.f, 0.f, 0.f, 0.f};
  for (int i = 0; i < nsplit; ++i) {
    f32x4 v = *(const f32x4*)(part + (long)i * MN + i4 * 4);
    s += v;
  }
  f32x4 bv = *(const f32x4*)(bias + ((i4 * 4) & (N - 1)));
  f32x4 g;
  g.x = 1.f / (1.f + __expf(-(s.x + bv.x)));
  g.y = 1.f / (1.f + __expf(-(s.y + bv.y)));
  g.z = 1.f / (1.f + __expf(-(s.z + bv.z)));
  g.w = 1.f / (1.f + __expf(-(s.w + bv.w)));
  if (outF) *(f32x4*)(outF + i4 * 4) = g;
  if (outB) {
    union { __hip_bfloat16 h[4]; unsigned long long u; } pk;
    pk.h[0] = __float2bfloat16(g.x); pk.h[1] = __float2bfloat16(g.y);
    pk.h[2] = __float2bfloat16(g.z); pk.h[3] = __float2bfloat16(g.w);
    *((unsigned long long*)outB + i4) = pk.u;
  }
}

// ---------- kernel 6: weighted[b][p][l] partials = sum_c g[b][p*C+c] * x[b][c][l] ----------
// grid (4 l-blocks, 32 b, 8 c-splits of 256); g block-uniform -> scalar loads.
__global__ __launch_bounds__(256) void ein_partial_kernel(const float* __restrict__ x,
                                                          const float* __restrict__ g,
                                                          float* __restrict__ part) {
  int l = blockIdx.x * 256 + threadIdx.x;
  int b = blockIdx.y;
  int s = blockIdx.z;
  int c0 = s * 256;
  const float* xp = x + ((long)b * CC + c0) * LL + l;
  const float* gp = g + (long)b * NOUT + c0;
  bool act = l < LL;
  float acc[PP] = {0.f, 0.f, 0.f, 0.f, 0.f, 0.f, 0.f, 0.f};
#pragma unroll 8
  for (int i = 0; i < 256; ++i) {
    float xv = act ? xp[(long)i * LL] : 0.f;
#pragma unroll
    for (int p = 0; p < PP; ++p) acc[p] += gp[p * CC + i] * xv;
  }
  if (act) {
    float* pp = part + (long)(s * BB + b) * PP * LL + l;
#pragma unroll
    for (int p = 0; p < PP; ++p) pp[(long)p * LL] = acc[p];
  }
}

// ---------- kernel 7: reduce c-splits, /C, float4-wide ----------
__global__ __launch_bounds__(256) void ein_reduce_kernel(const float* __restrict__ part,
                                                         float* __restrict__ outw) {
  int i4 = blockIdx.x * 256 + threadIdx.x;  // 57024 = 891*256/4 lanes
  if (i4 >= (BB * PP * LL) / 4) return;
  f32x4 s = {0.f, 0.f, 0.f, 0.f};
#pragma unroll
  for (int i = 0; i < 8; ++i) {
    f32x4 v = *(const f32x4*)(part + (long)i * (BB * PP * LL) + i4 * 4);
    s += v;
  }
  const float inv = 1.0f / (float)CC;
  f32x4 o = s * inv;
  *(f32x4*)(outw + i4 * 4) = o;
}

extern "C" void kernel_launch(void* const* d_in, const int* in_sizes, int n_in,
                              void* d_out, int out_size, void* d_ws, size_t ws_size,
                              hipStream_t stream) {
  const float* x     = (const float*)d_in[0];
  const float* fc1_w = (const float*)d_in[1];
  const float* fc1_b = (const float*)d_in[2];
  const float* fc2_w = (const float*)d_in[3];
  const float* fc2_b = (const float*)d_in[4];
  float* out = (float*)d_out;

  char* ws = (char*)d_ws;
  __hip_bfloat16* pooled = (__hip_bfloat16*)ws;              // 32*2048*2   = 128 KB
  __hip_bfloat16* hbuf   = (__hip_bfloat16*)(ws + 131072);   // 32*8192*2   = 512 KB
  float* part            = (float*)(ws + 655360);            // max 33.6 MB (reused per stage)

  pool_kernel<<<BB * CC / 4, 256, 0, stream>>>(x, pooled);

  // fc1: T=2, N=8192, K=2048, 16-way split-K (kc=128) -> 1024 blocks   [R10 config]
  fc_kernel<2><<<dim3(HIDN / 128, 16), 256, 0, stream>>>(pooled, fc1_w, part, HIDN, CC, CC / 16);
  fc_reduce_kernel<<<BB * HIDN / 1024, 256, 0, stream>>>(part, 16, BB * HIDN, HIDN, fc1_b,
                                                         nullptr, hbuf);

  // fc2: T=2, N=16384, K=8192, 16-way split-K (kc=512) -> 2048 blocks  [R12 probe: was T=4/1024]
  fc_kernel<2><<<dim3(NOUT / 128, 16), 256, 0, stream>>>(hbuf, fc2_w, part, NOUT, HIDN, HIDN / 16);
  fc_reduce_kernel<<<BB * NOUT / 1024, 256, 0, stream>>>(part, 16, BB * NOUT, NOUT, fc2_b,
                                                         out, nullptr);

  // ein: 8 c-splits of 256 -> 1024 blocks   [R10 config]
  ein_partial_kernel<<<dim3(4, BB, 8), 256, 0, stream>>>(x, out, part);
  ein_reduce_kernel<<<(BB * PP * LL / 4 + 255) / 256, 256, 0, stream>>>(part, out + BB * PP * CC);
}